// Round 1
// baseline (1075.099 us; speedup 1.0000x reference)
//
#include <hip/hip_runtime.h>

#define M_MEMBERS 8
#define E_DIM 512
#define H_DIM 1024
#define V_DIM 4096
#define BI_DIM 4096

typedef __bf16 bf16x8 __attribute__((ext_vector_type(8)));
typedef float f32x4 __attribute__((ext_vector_type(4)));

__device__ __forceinline__ unsigned short f2b(float f) {
    unsigned u = __builtin_bit_cast(unsigned, f);
    u += 0x7fffu + ((u >> 16) & 1u);   // round-to-nearest-even
    return (unsigned short)(u >> 16);
}
__device__ __forceinline__ float b2f(unsigned short s) {
    return __builtin_bit_cast(float, (unsigned)s << 16);
}

// ---- async global->LDS, 16B per lane. LDS dest is wave-uniform base + lane*16.
typedef unsigned int __attribute__((address_space(1)))* gas_ptr;
typedef unsigned int __attribute__((address_space(3)))* las_ptr;

__device__ __forceinline__ void async16(const void* g, void* l) {
    __builtin_amdgcn_global_load_lds((gas_ptr)(unsigned long long)g,
                                     (las_ptr)(unsigned)(unsigned long long)l,
                                     16, 0, 0);
}

// ---------------- conversion: fp32 -> bf16, row-major ----------------
__global__ __launch_bounds__(256) void cvt_bf16(const float* __restrict__ in,
                                                unsigned short* __restrict__ out, long n) {
    long i = ((long)blockIdx.x * blockDim.x + threadIdx.x) * 4;
    if (i + 3 < n) {
        float4 v = *(const float4*)(in + i);
        ushort4 o;
        o.x = f2b(v.x); o.y = f2b(v.y); o.z = f2b(v.z); o.w = f2b(v.w);
        *(ushort4*)(out + i) = o;
    }
}

// ------- conversion: fp32 [z][R][C] -> bf16 [z][C][R] (transpose per member) -------
__global__ __launch_bounds__(256) void cvt_t(const float* __restrict__ in,
                                             unsigned short* __restrict__ out,
                                             int R, int C) {
    __shared__ unsigned short tile[32][34];
    const long mb = blockIdx.z;
    const float* inp = in + mb * (long)R * C;
    unsigned short* outp = out + mb * (long)R * C;
    const int c0 = blockIdx.x * 32, r0 = blockIdx.y * 32;
    const int tx = threadIdx.x, ty = threadIdx.y;   // blockDim (32, 8)
#pragma unroll
    for (int i = 0; i < 32; i += 8)
        tile[ty + i][tx] = f2b(inp[(long)(r0 + ty + i) * C + c0 + tx]);
    __syncthreads();
#pragma unroll
    for (int i = 0; i < 32; i += 8)
        outp[(long)(c0 + ty + i) * R + r0 + tx] = tile[tx][ty + i];
}

// ---------------- GEMM: C[128x128/block] = A[M x K] * Bt[N x K]^T + bias ----------------
// A row-major [rows][K] bf16, Bt row-major [N][K] bf16 (i.e. B transposed).
// m97 structure: BK=32, 256 threads (4 waves in 2x2), each wave 64x64 via 4x4 MFMA 16x16x32.
template <bool OUT_BF16>
__global__ __launch_bounds__(256, 2) void gemm_bt(
    const unsigned short* __restrict__ A,
    const unsigned short* __restrict__ Bt,
    const float* __restrict__ bias,
    void* __restrict__ Cout,
    int N, int K,
    long sA, long sB, long sBias, long sC)
{
    __shared__ __align__(16) unsigned short ldsA[128 * 32];
    __shared__ __align__(16) unsigned short ldsB[128 * 32];

    const int tid  = threadIdx.x;
    const int wave = tid >> 6;
    const int lane = tid & 63;
    const int wr   = wave >> 1;       // 0/1: which 64-row half
    const int wc   = wave & 1;        // 0/1: which 64-col half
    const long mb  = blockIdx.z;

    const unsigned short* Ag = A  + mb * sA + (long)blockIdx.x * 128 * K;
    const unsigned short* Bg = Bt + mb * sB + (long)blockIdx.y * 128 * K;

    // staging: each wave covers 16 rows x 32 k per call (1 KB), 2 passes for 128 rows
    const int srow = wave * 16 + (lane >> 2);
    const int scol = (lane & 3) * 8;
    const unsigned short* agp = Ag + (long)srow * K + scol;
    const unsigned short* bgp = Bg + (long)srow * K + scol;
    unsigned short* la_w = &ldsA[wave * 16 * 32];
    unsigned short* lb_w = &ldsB[wave * 16 * 32];

    f32x4 acc[4][4] = {};

    const int frow = lane & 15;
    const int qk   = (lane >> 4) * 8;  // k offset within BK=32: A[m][k=quad*8+j]

    for (int k0 = 0; k0 < K; k0 += 32) {
        async16(agp + k0,            la_w);
        async16(agp + k0 + 64 * K,   la_w + 64 * 32);
        async16(bgp + k0,            lb_w);
        async16(bgp + k0 + 64 * K,   lb_w + 64 * 32);
        __syncthreads();   // drains vmcnt before barrier (compiler-inserted)

        bf16x8 af[4], bfr[4];
#pragma unroll
        for (int t = 0; t < 4; t++) {
            af[t]  = *(const bf16x8*)&ldsA[(wr * 64 + t * 16 + frow) * 32 + qk];
            bfr[t] = *(const bf16x8*)&ldsB[(wc * 64 + t * 16 + frow) * 32 + qk];
        }
#pragma unroll
        for (int i = 0; i < 4; i++)
#pragma unroll
            for (int j = 0; j < 4; j++)
                acc[i][j] = __builtin_amdgcn_mfma_f32_16x16x32_bf16(af[i], bfr[j], acc[i][j], 0, 0, 0);
        __syncthreads();
    }

    // epilogue: C/D layout col=lane&15, row=(lane>>4)*4+reg
    const int row0 = blockIdx.x * 128 + wr * 64 + (lane >> 4) * 4;
    const int col0 = blockIdx.y * 128 + wc * 64 + (lane & 15);
    const float* bp = bias + mb * sBias;
#pragma unroll
    for (int tj = 0; tj < 4; tj++) {
        const int c = col0 + tj * 16;
        const float bv = bp[c];
#pragma unroll
        for (int ti = 0; ti < 4; ti++) {
            const int r = row0 + ti * 16;
#pragma unroll
            for (int e = 0; e < 4; e++) {
                float v = acc[ti][tj][e] + bv;
                if (OUT_BF16)
                    ((unsigned short*)Cout)[mb * sC + (long)(r + e) * N + c] = f2b(v);
                else
                    ((float*)Cout)[mb * sC + (long)(r + e) * N + c] = v;
            }
        }
    }
}

// ---------------- LayerNorm + SiLU, in place on bf16 h [M*BI][H] ----------------
__global__ __launch_bounds__(256) void ln_silu(unsigned short* __restrict__ h,
                                               const float* __restrict__ lnw,
                                               const float* __restrict__ lnb) {
    const long row = blockIdx.x;
    const int m = (int)(row >> 12);   // row / BI
    unsigned short* hp = h + row * H_DIM;
    const int tid = threadIdx.x;

    ushort4 raw = *(const ushort4*)(hp + tid * 4);
    float v0 = b2f(raw.x), v1 = b2f(raw.y), v2 = b2f(raw.z), v3 = b2f(raw.w);
    float s  = v0 + v1 + v2 + v3;
    float s2 = v0 * v0 + v1 * v1 + v2 * v2 + v3 * v3;
#pragma unroll
    for (int off = 32; off > 0; off >>= 1) {
        s  += __shfl_down(s,  off, 64);
        s2 += __shfl_down(s2, off, 64);
    }
    __shared__ float wsum[4], wsq[4];
    const int wave = tid >> 6, lane = tid & 63;
    if (lane == 0) { wsum[wave] = s; wsq[wave] = s2; }
    __syncthreads();
    const float S  = wsum[0] + wsum[1] + wsum[2] + wsum[3];
    const float S2 = wsq[0] + wsq[1] + wsq[2] + wsq[3];
    const float mu  = S * (1.0f / H_DIM);
    const float var = S2 * (1.0f / H_DIM) - mu * mu;
    const float rs  = rsqrtf(var + 1e-5f);

    const float* wp = lnw + (long)m * H_DIM + tid * 4;
    const float* bp = lnb + (long)m * H_DIM + tid * 4;
    float t0 = (v0 - mu) * rs * wp[0] + bp[0];
    float t1 = (v1 - mu) * rs * wp[1] + bp[1];
    float t2 = (v2 - mu) * rs * wp[2] + bp[2];
    float t3 = (v3 - mu) * rs * wp[3] + bp[3];
    ushort4 o;
    o.x = f2b(t0 / (1.0f + __expf(-t0)));
    o.y = f2b(t1 / (1.0f + __expf(-t1)));
    o.z = f2b(t2 / (1.0f + __expf(-t2)));
    o.w = f2b(t3 / (1.0f + __expf(-t3)));
    *(ushort4*)(hp + tid * 4) = o;
}

extern "C" void kernel_launch(void* const* d_in, const int* in_sizes, int n_in,
                              void* d_out, int out_size, void* d_ws, size_t ws_size,
                              hipStream_t stream) {
    (void)in_sizes; (void)n_in; (void)out_size; (void)ws_size;
    const float* x   = (const float*)d_in[0];
    const float* W1  = (const float*)d_in[1];
    const float* b1  = (const float*)d_in[2];
    const float* lnw = (const float*)d_in[3];
    const float* lnb = (const float*)d_in[4];
    const float* W2  = (const float*)d_in[5];
    const float* b2  = (const float*)d_in[6];
    float* out = (float*)d_out;

    const size_t nX  = (size_t)M_MEMBERS * BI_DIM * E_DIM;   // 16,777,216
    const size_t nW1 = (size_t)M_MEMBERS * E_DIM * H_DIM;    //  4,194,304
    const size_t nW2 = (size_t)M_MEMBERS * H_DIM * V_DIM;    // 33,554,432
    // ws layout (bf16 elems): xb | w1t | w2t | hb   -> 176 MB total
    unsigned short* xb  = (unsigned short*)d_ws;
    unsigned short* w1t = xb  + nX;
    unsigned short* w2t = w1t + nW1;
    unsigned short* hb  = w2t + nW2;

    cvt_bf16<<<(unsigned)(nX / 1024), 256, 0, stream>>>(x, xb, (long)nX);
    cvt_t<<<dim3(H_DIM / 32, E_DIM / 32, M_MEMBERS), dim3(32, 8), 0, stream>>>(W1, w1t, E_DIM, H_DIM);
    cvt_t<<<dim3(V_DIM / 32, H_DIM / 32, M_MEMBERS), dim3(32, 8), 0, stream>>>(W2, w2t, H_DIM, V_DIM);

    // GEMM1: h = x @ W1 + b1  (bf16 out, pre-LN)
    gemm_bt<true><<<dim3(BI_DIM / 128, H_DIM / 128, M_MEMBERS), 256, 0, stream>>>(
        xb, w1t, b1, hb, H_DIM, E_DIM,
        (long)BI_DIM * E_DIM, (long)H_DIM * E_DIM, (long)H_DIM, (long)BI_DIM * H_DIM);

    ln_silu<<<dim3(M_MEMBERS * BI_DIM), 256, 0, stream>>>(hb, lnw, lnb);

    // GEMM2: out = h @ W2 + b2  (fp32 out)
    gemm_bt<false><<<dim3(BI_DIM / 128, V_DIM / 128, M_MEMBERS), 256, 0, stream>>>(
        hb, w2t, b2, out, V_DIM, H_DIM,
        (long)BI_DIM * H_DIM, (long)V_DIM * H_DIM, (long)V_DIM, (long)BI_DIM * V_DIM);
}